// Round 1
// baseline (352.078 us; speedup 1.0000x reference)
//
#include <hip/hip_runtime.h>
#include <stdint.h>

#define D_IN 128
#define D_OUT 128
#define NREL 8
#define NBASE 4

typedef __attribute__((ext_vector_type(8))) short short8;
typedef __attribute__((ext_vector_type(4))) float floatx4;

__device__ __forceinline__ unsigned short f2bf(float f) {
  unsigned int u = __float_as_uint(f);
  u += 0x7fffu + ((u >> 16) & 1u);
  return (unsigned short)(u >> 16);
}
__device__ __forceinline__ float bflo(unsigned int u) { return __uint_as_float(u << 16); }
__device__ __forceinline__ float bfhi(unsigned int u) { return __uint_as_float(u & 0xffff0000u); }

// ---------- 1) cast X fp32 -> bf16 ----------
__global__ void k_cast_x(const float4* __restrict__ X, ushort4* __restrict__ Xb, int n4) {
  int i = blockIdx.x * blockDim.x + threadIdx.x;
  if (i >= n4) return;
  float4 v = X[i];
  ushort4 o;
  o.x = f2bf(v.x); o.y = f2bf(v.y); o.z = f2bf(v.z); o.w = f2bf(v.w);
  Xb[i] = o;
}

// ---------- 2) W2T[c][k] = w_bases[b][k][o], c = o*4+b  (bf16, [512][128]) ----------
__global__ void k_build_w2t(const float* __restrict__ w_bases, unsigned short* __restrict__ W2T) {
  int t = blockIdx.x * 256 + threadIdx.x;
  if (t >= 512 * 128) return;
  int c = t >> 7, k = t & 127;
  int b = c & 3, o = c >> 2;
  W2T[t] = f2bf(w_bases[(b * D_IN + k) * D_OUT + o]);
}

// ---------- 3) GEMM: Y[n][c] = sum_k Xb[n][k]*W2T[c][k];  Y bf16 [N][512] ----------
// 128x128 tile per block, 4 waves in 2x2, each wave 64x64 via 4x4 of 16x16x32 MFMA.
// A staged in LDS (padded pitch); B (tiny, 128KB total) read straight from cache.
__global__ __launch_bounds__(256, 2)
void k_gemm(const unsigned short* __restrict__ Xb, const unsigned short* __restrict__ W2T,
            unsigned short* __restrict__ Y, int Nn) {
  __shared__ unsigned short As[128][136];
  const int tid = threadIdx.x;
  const int bm = blockIdx.x, bn = blockIdx.y;
#pragma unroll
  for (int it = 0; it < 8; ++it) {
    int idx = tid + it * 256;
    int r = idx >> 4, ck = idx & 15;
    int grow = bm * 128 + r;
    uint4 va = make_uint4(0u, 0u, 0u, 0u);
    if (grow < Nn) va = ((const uint4*)(Xb + (size_t)grow * 128))[ck];
    *(uint4*)&As[r][ck * 8] = va;
  }
  __syncthreads();
  const int wave = tid >> 6, lane = tid & 63;
  const int wm = (wave & 1) << 6, wn = (wave >> 1) << 6;
  const int q = lane >> 4, r16 = lane & 15;
  const floatx4 zero = {0.f, 0.f, 0.f, 0.f};
  floatx4 acc[4][4];
#pragma unroll
  for (int i = 0; i < 4; ++i)
#pragma unroll
    for (int j = 0; j < 4; ++j) acc[i][j] = zero;

  const unsigned short* Bbase = W2T + (size_t)(bn * 128) * 128;
#pragma unroll
  for (int k0 = 0; k0 < 128; k0 += 32) {
    int ka = k0 + q * 8;
    short8 af[4], bfv[4];
#pragma unroll
    for (int i = 0; i < 4; ++i)
      af[i] = *(const short8*)&As[wm + i * 16 + r16][ka];
#pragma unroll
    for (int j = 0; j < 4; ++j)
      bfv[j] = *(const short8*)(Bbase + (size_t)(wn + j * 16 + r16) * 128 + ka);
#pragma unroll
    for (int i = 0; i < 4; ++i)
#pragma unroll
      for (int j = 0; j < 4; ++j)
        acc[i][j] = __builtin_amdgcn_mfma_f32_16x16x32_bf16(af[i], bfv[j], acc[i][j], 0, 0, 0);
  }
  // epilogue: C/D layout col=lane&15, row=(lane>>4)*4+p  [m89/m91-verified]
#pragma unroll
  for (int i = 0; i < 4; ++i) {
#pragma unroll
    for (int j = 0; j < 4; ++j) {
#pragma unroll
      for (int p = 0; p < 4; ++p) {
        int row = wm + i * 16 + q * 4 + p;
        int col = wn + j * 16 + r16;
        int grow = bm * 128 + row;
        if (grow < Nn) Y[(size_t)grow * 512 + bn * 128 + col] = f2bf(acc[i][j][p]);
      }
    }
  }
}

// ---------- 4) CSR build ----------
__global__ void k_count(const int* __restrict__ dst, int* __restrict__ counts, int E) {
  int i = blockIdx.x * blockDim.x + threadIdx.x;
  if (i < E) atomicAdd(&counts[dst[i]], 1);
}

__global__ void k_scan1(const int* __restrict__ counts, int* __restrict__ localsc,
                        int* __restrict__ bsum, int Nn) {
  __shared__ int s[256];
  int i = blockIdx.x * 256 + threadIdx.x;
  int v = (i < Nn) ? counts[i] : 0;
  s[threadIdx.x] = v;
  __syncthreads();
  for (int off = 1; off < 256; off <<= 1) {
    int t = 0;
    if (threadIdx.x >= off) t = s[threadIdx.x - off];
    __syncthreads();
    s[threadIdx.x] += t;
    __syncthreads();
  }
  if (i < Nn) localsc[i] = s[threadIdx.x] - v;  // exclusive within block
  if (threadIdx.x == 255) bsum[blockIdx.x] = s[255];
}

__global__ void k_scan2(int* __restrict__ bsum, int nb) {
  __shared__ int s[512];
  int t = threadIdx.x;
  int v = (t < nb) ? bsum[t] : 0;
  s[t] = v;
  __syncthreads();
  for (int off = 1; off < 512; off <<= 1) {
    int u = 0;
    if (t >= off) u = s[t - off];
    __syncthreads();
    s[t] += u;
    __syncthreads();
  }
  if (t < nb) bsum[t] = s[t] - v;  // exclusive
}

__global__ void k_scan3(const int* __restrict__ localsc, const int* __restrict__ bsum,
                        int* __restrict__ offsets, int* __restrict__ cursor, int Nn, int E) {
  int i = blockIdx.x * 256 + threadIdx.x;
  if (i < Nn) {
    int v = localsc[i] + bsum[blockIdx.x];
    offsets[i] = v;
    cursor[i] = v;
  }
  if (i == 0) offsets[Nn] = E;
}

__global__ void k_bucket(const int* __restrict__ src, const int* __restrict__ dst,
                         const int* __restrict__ rel, const float* __restrict__ val,
                         int* __restrict__ cursor, uint2* __restrict__ bucket, int E) {
  int i = blockIdx.x * blockDim.x + threadIdx.x;
  if (i >= E) return;
  int d = dst[i];
  int pos = atomicAdd(&cursor[d], 1);
  bucket[pos] = make_uint2((unsigned)src[i] | ((unsigned)rel[i] << 21), __float_as_uint(val[i]));
}

// ---------- 5) per-dst gather-accumulate (atomic-free) ----------
// One wave per destination node; lane covers 2 output features.
// Y row layout: [o][b] interleaved -> lane's uint4 = {(2l,b0..3),(2l+1,b0..3)} bf16.
__global__ __launch_bounds__(256)
void k_gather(const uint2* __restrict__ bucket, const int* __restrict__ offsets,
              const float* __restrict__ w_rel_g, const uint4* __restrict__ Y4,
              float2* __restrict__ out, int Nn) {
  __shared__ float wr[NREL * NBASE];
  if (threadIdx.x < NREL * NBASE) wr[threadIdx.x] = w_rel_g[threadIdx.x];
  __syncthreads();
  const int wave = threadIdx.x >> 6, lane = threadIdx.x & 63;
  const int dst = blockIdx.x * 4 + wave;
  if (dst >= Nn) return;
  const int s = offsets[dst], e = offsets[dst + 1];
  float ax = 0.f, ay = 0.f;
  for (int i = s; i < e; ++i) {
    uint2 m = bucket[i];
    unsigned srcn = m.x & 0x1FFFFFu;
    unsigned rel = m.x >> 21;
    float val = __uint_as_float(m.y);
    float c0 = val * wr[rel * 4 + 0];
    float c1 = val * wr[rel * 4 + 1];
    float c2 = val * wr[rel * 4 + 2];
    float c3 = val * wr[rel * 4 + 3];
    uint4 y = Y4[((size_t)srcn << 6) + lane];
    ax += c0 * bflo(y.x) + c1 * bfhi(y.x) + c2 * bflo(y.y) + c3 * bfhi(y.y);
    ay += c0 * bflo(y.z) + c1 * bfhi(y.z) + c2 * bflo(y.w) + c3 * bfhi(y.w);
  }
  out[((size_t)dst << 6) + lane] = make_float2(ax, ay);
}

extern "C" void kernel_launch(void* const* d_in, const int* in_sizes, int n_in,
                              void* d_out, int out_size, void* d_ws, size_t ws_size,
                              hipStream_t stream) {
  const float* X = (const float*)d_in[0];
  const int* esrc = (const int*)d_in[1];
  const int* edst = (const int*)d_in[2];
  const int* erel = (const int*)d_in[3];
  const float* eval_ = (const float*)d_in[4];
  const float* w_bases = (const float*)d_in[5];
  const float* w_rel = (const float*)d_in[6];
  const int Nn = in_sizes[0] / D_IN;  // 100000
  const int E = in_sizes[1];          // 640000

  char* ws = (char*)d_ws;
  size_t off = 0;
  auto alloc = [&](size_t bytes) -> char* {
    char* p = ws + off;
    off += (bytes + 255) & ~(size_t)255;
    return p;
  };
  unsigned short* Xb = (unsigned short*)alloc((size_t)Nn * D_IN * 2);        // 25.6 MB
  unsigned short* W2T = (unsigned short*)alloc((size_t)512 * 128 * 2);       // 128 KB
  unsigned short* Y = (unsigned short*)alloc((size_t)Nn * 512 * 2);          // 102.4 MB
  int* counts = (int*)alloc((size_t)Nn * 4);
  int* cursor = (int*)alloc((size_t)Nn * 4);
  int* offsets = (int*)alloc((size_t)(Nn + 1) * 4);
  int* localsc = (int*)alloc((size_t)Nn * 4);
  int* bsum = (int*)alloc(4096);
  uint2* bucket = (uint2*)alloc((size_t)E * 8);                              // 5.1 MB
  (void)ws_size;

  hipMemsetAsync(counts, 0, (size_t)Nn * 4, stream);

  // GEMM path
  int n4 = Nn * D_IN / 4;
  k_cast_x<<<(n4 + 255) / 256, 256, 0, stream>>>((const float4*)X, (ushort4*)Xb, n4);
  k_build_w2t<<<(512 * 128 + 255) / 256, 256, 0, stream>>>(w_bases, W2T);
  dim3 ggrid((Nn + 127) / 128, 4);
  k_gemm<<<ggrid, 256, 0, stream>>>(Xb, W2T, Y, Nn);

  // CSR build
  k_count<<<(E + 255) / 256, 256, 0, stream>>>(edst, counts, E);
  int nb = (Nn + 255) / 256;
  k_scan1<<<nb, 256, 0, stream>>>(counts, localsc, bsum, Nn);
  k_scan2<<<1, 512, 0, stream>>>(bsum, nb);
  k_scan3<<<nb, 256, 0, stream>>>(localsc, bsum, offsets, cursor, Nn, E);
  k_bucket<<<(E + 255) / 256, 256, 0, stream>>>(esrc, edst, erel, eval_, cursor, bucket, E);

  // gather-accumulate
  k_gather<<<(Nn + 3) / 4, 256, 0, stream>>>(bucket, offsets, w_rel, (const uint4*)Y,
                                             (float2*)d_out, Nn);
}

// Round 2
// 326.717 us; speedup vs baseline: 1.0776x; 1.0776x over previous
//
#include <hip/hip_runtime.h>
#include <stdint.h>

#define D_IN 128
#define D_OUT 128
#define NREL 8
#define NBASE 4

typedef __attribute__((ext_vector_type(8))) short short8;
typedef __attribute__((ext_vector_type(4))) float floatx4;

__device__ __forceinline__ unsigned short f2bf(float f) {
  unsigned int u = __float_as_uint(f);
  u += 0x7fffu + ((u >> 16) & 1u);
  return (unsigned short)(u >> 16);
}
__device__ __forceinline__ unsigned pack2bf(float lo, float hi) {
  return (unsigned)f2bf(lo) | ((unsigned)f2bf(hi) << 16);
}
__device__ __forceinline__ float bflo(unsigned int u) { return __uint_as_float(u << 16); }
__device__ __forceinline__ float bfhi(unsigned int u) { return __uint_as_float(u & 0xffff0000u); }

// ---------- 1) cast X fp32 -> bf16 [N][128] ----------
__global__ void k_cast_x(const float4* __restrict__ X, ushort4* __restrict__ Xb, int n4) {
  int i = blockIdx.x * blockDim.x + threadIdx.x;
  if (i >= n4) return;
  float4 v = X[i];
  ushort4 o;
  o.x = f2bf(v.x); o.y = f2bf(v.y); o.z = f2bf(v.z); o.w = f2bf(v.w);
  Xb[i] = o;
}

// ---------- 2) W2T[o][c] = w_bases[b][k][o], c = k*4+b  (bf16, [128][512]) ----------
__global__ void k_build_w2t(const float* __restrict__ w_bases, unsigned short* __restrict__ W2T) {
  int t = blockIdx.x * 256 + threadIdx.x;
  if (t >= 128 * 512) return;
  int o = t >> 9, c = t & 511;
  int k = c >> 2, b = c & 3;
  W2T[t] = f2bf(w_bases[(b * D_IN + k) * D_OUT + o]);
}

// ---------- 3) CSR build ----------
__global__ void k_count(const int* __restrict__ dst, int* __restrict__ counts, int E) {
  int i = blockIdx.x * blockDim.x + threadIdx.x;
  if (i < E) atomicAdd(&counts[dst[i]], 1);
}

__global__ void k_scan1(const int* __restrict__ counts, int* __restrict__ localsc,
                        int* __restrict__ bsum, int Nn) {
  __shared__ int s[256];
  int i = blockIdx.x * 256 + threadIdx.x;
  int v = (i < Nn) ? counts[i] : 0;
  s[threadIdx.x] = v;
  __syncthreads();
  for (int off = 1; off < 256; off <<= 1) {
    int t = 0;
    if (threadIdx.x >= off) t = s[threadIdx.x - off];
    __syncthreads();
    s[threadIdx.x] += t;
    __syncthreads();
  }
  if (i < Nn) localsc[i] = s[threadIdx.x] - v;
  if (threadIdx.x == 255) bsum[blockIdx.x] = s[255];
}

__global__ void k_scan2(int* __restrict__ bsum, int nb) {
  __shared__ int s[512];
  int t = threadIdx.x;
  int v = (t < nb) ? bsum[t] : 0;
  s[t] = v;
  __syncthreads();
  for (int off = 1; off < 512; off <<= 1) {
    int u = 0;
    if (t >= off) u = s[t - off];
    __syncthreads();
    s[t] += u;
    __syncthreads();
  }
  if (t < nb) bsum[t] = s[t] - v;
}

__global__ void k_scan3(const int* __restrict__ localsc, const int* __restrict__ bsum,
                        int* __restrict__ offsets, int* __restrict__ cursor, int Nn, int E) {
  int i = blockIdx.x * 256 + threadIdx.x;
  if (i < Nn) {
    int v = localsc[i] + bsum[blockIdx.x];
    offsets[i] = v;
    cursor[i] = v;
  }
  if (i == 0) offsets[Nn] = E;
}

__global__ void k_bucket(const int* __restrict__ src, const int* __restrict__ dst,
                         const int* __restrict__ rel, const float* __restrict__ val,
                         int* __restrict__ cursor, uint2* __restrict__ bucket, int E) {
  int i = blockIdx.x * blockDim.x + threadIdx.x;
  if (i >= E) return;
  int d = dst[i];
  int pos = atomicAdd(&cursor[d], 1);
  bucket[pos] = make_uint2((unsigned)src[i] | ((unsigned)rel[i] << 21), __float_as_uint(val[i]));
}

// ---------- 4) per-dst basis-space aggregation (atomic-free) ----------
// One wave per dst. Lane l covers input features k = {2l, 2l+1} (one uint load
// of Xb per edge = coalesced 256 B wave read of a 25.6 MB L3-resident table).
// acc[b][j]: 8 fp32/lane. Output agg[n][c] bf16, c = k*4+b -> lane writes
// 8 contiguous bf16 = one uint4.
__global__ __launch_bounds__(256)
void k_gather_agg(const uint2* __restrict__ bucket, const int* __restrict__ offsets,
                  const float* __restrict__ w_rel_g, const unsigned* __restrict__ Xb2,
                  uint4* __restrict__ agg4, int Nn) {
  __shared__ float wr[NREL * NBASE];
  if (threadIdx.x < NREL * NBASE) wr[threadIdx.x] = w_rel_g[threadIdx.x];
  __syncthreads();
  const int wave = threadIdx.x >> 6, lane = threadIdx.x & 63;
  const int dst = blockIdx.x * 4 + wave;
  if (dst >= Nn) return;
  const int s = offsets[dst], e = offsets[dst + 1];
  float a00 = 0.f, a10 = 0.f, a20 = 0.f, a30 = 0.f;  // k = 2l
  float a01 = 0.f, a11 = 0.f, a21 = 0.f, a31 = 0.f;  // k = 2l+1
  for (int i = s; i < e; ++i) {
    uint2 m = bucket[i];
    unsigned srcn = m.x & 0x1FFFFFu;
    unsigned rel = m.x >> 21;
    float val = __uint_as_float(m.y);
    float c0 = val * wr[rel * 4 + 0];
    float c1 = val * wr[rel * 4 + 1];
    float c2 = val * wr[rel * 4 + 2];
    float c3 = val * wr[rel * 4 + 3];
    unsigned x = Xb2[((size_t)srcn << 6) + lane];
    float x0 = bflo(x), x1 = bfhi(x);
    a00 += c0 * x0; a10 += c1 * x0; a20 += c2 * x0; a30 += c3 * x0;
    a01 += c0 * x1; a11 += c1 * x1; a21 += c2 * x1; a31 += c3 * x1;
  }
  uint4 o;
  o.x = pack2bf(a00, a10);  // c = 8l+0, 8l+1
  o.y = pack2bf(a20, a30);  // c = 8l+2, 8l+3
  o.z = pack2bf(a01, a11);  // c = 8l+4, 8l+5
  o.w = pack2bf(a21, a31);  // c = 8l+6, 8l+7
  agg4[((size_t)dst << 6) + lane] = o;
}

// ---------- 5) GEMM: out[n][o] = sum_c agg[n][c] * W2T[o][c], K=512 ----------
// 128-row tile per block, full 128 output cols. 4 waves 2x2 (wm,wn in {0,64}).
// A staged in LDS per 128-k chunk; B (128 KB, shared by all blocks) from L2.
__global__ __launch_bounds__(256, 2)
void k_gemm(const unsigned short* __restrict__ agg, const unsigned short* __restrict__ W2T,
            float* __restrict__ out, int Nn) {
  __shared__ unsigned short As[128][136];
  const int tid = threadIdx.x;
  const int bm = blockIdx.x;
  const int wave = tid >> 6, lane = tid & 63;
  const int wm = (wave & 1) << 6, wn = (wave >> 1) << 6;
  const int q = lane >> 4, r16 = lane & 15;
  const floatx4 zero = {0.f, 0.f, 0.f, 0.f};
  floatx4 acc[4][4];
#pragma unroll
  for (int i = 0; i < 4; ++i)
#pragma unroll
    for (int j = 0; j < 4; ++j) acc[i][j] = zero;

  for (int kc = 0; kc < 4; ++kc) {
    // stage A chunk: rows bm*128..+128, k cols kc*128..+128
#pragma unroll
    for (int it = 0; it < 8; ++it) {
      int idx = tid + it * 256;
      int r = idx >> 4, ck = idx & 15;
      int grow = bm * 128 + r;
      uint4 va = make_uint4(0u, 0u, 0u, 0u);
      if (grow < Nn) va = ((const uint4*)(agg + (size_t)grow * 512 + kc * 128))[ck];
      *(uint4*)&As[r][ck * 8] = va;
    }
    __syncthreads();
#pragma unroll
    for (int k0 = 0; k0 < 128; k0 += 32) {
      int ka = k0 + q * 8;
      short8 af[4], bfv[4];
#pragma unroll
      for (int i = 0; i < 4; ++i)
        af[i] = *(const short8*)&As[wm + i * 16 + r16][ka];
#pragma unroll
      for (int j = 0; j < 4; ++j)
        bfv[j] = *(const short8*)(W2T + (size_t)(wn + j * 16 + r16) * 512 + kc * 128 + ka);
#pragma unroll
      for (int i = 0; i < 4; ++i)
#pragma unroll
        for (int j = 0; j < 4; ++j)
          acc[i][j] = __builtin_amdgcn_mfma_f32_16x16x32_bf16(af[i], bfv[j], acc[i][j], 0, 0, 0);
    }
    __syncthreads();
  }
  // epilogue: C/D layout col=lane&15, row=(lane>>4)*4+p  [m89/m91-verified]
#pragma unroll
  for (int i = 0; i < 4; ++i) {
#pragma unroll
    for (int j = 0; j < 4; ++j) {
#pragma unroll
      for (int p = 0; p < 4; ++p) {
        int row = wm + i * 16 + q * 4 + p;
        int col = wn + j * 16 + r16;
        int grow = bm * 128 + row;
        if (grow < Nn) out[(size_t)grow * 128 + col] = acc[i][j][p];
      }
    }
  }
}

extern "C" void kernel_launch(void* const* d_in, const int* in_sizes, int n_in,
                              void* d_out, int out_size, void* d_ws, size_t ws_size,
                              hipStream_t stream) {
  const float* X = (const float*)d_in[0];
  const int* esrc = (const int*)d_in[1];
  const int* edst = (const int*)d_in[2];
  const int* erel = (const int*)d_in[3];
  const float* eval_ = (const float*)d_in[4];
  const float* w_bases = (const float*)d_in[5];
  const float* w_rel = (const float*)d_in[6];
  const int Nn = in_sizes[0] / D_IN;  // 100000
  const int E = in_sizes[1];          // 640000

  char* ws = (char*)d_ws;
  size_t off = 0;
  auto alloc = [&](size_t bytes) -> char* {
    char* p = ws + off;
    off += (bytes + 255) & ~(size_t)255;
    return p;
  };
  unsigned short* Xb = (unsigned short*)alloc((size_t)Nn * D_IN * 2);     // 25.6 MB
  unsigned short* W2T = (unsigned short*)alloc((size_t)128 * 512 * 2);    // 128 KB
  unsigned short* agg = (unsigned short*)alloc((size_t)Nn * 512 * 2);     // 102.4 MB
  int* counts = (int*)alloc((size_t)Nn * 4);
  int* cursor = (int*)alloc((size_t)Nn * 4);
  int* offsets = (int*)alloc((size_t)(Nn + 1) * 4);
  int* localsc = (int*)alloc((size_t)Nn * 4);
  int* bsum = (int*)alloc(4096);
  uint2* bucket = (uint2*)alloc((size_t)E * 8);                           // 5.1 MB
  (void)ws_size;

  hipMemsetAsync(counts, 0, (size_t)Nn * 4, stream);

  int n4 = Nn * D_IN / 4;
  k_cast_x<<<(n4 + 255) / 256, 256, 0, stream>>>((const float4*)X, (ushort4*)Xb, n4);
  k_build_w2t<<<(128 * 512 + 255) / 256, 256, 0, stream>>>(w_bases, W2T);

  // CSR build
  k_count<<<(E + 255) / 256, 256, 0, stream>>>(edst, counts, E);
  int nb = (Nn + 255) / 256;
  k_scan1<<<nb, 256, 0, stream>>>(counts, localsc, bsum, Nn);
  k_scan2<<<1, 512, 0, stream>>>(bsum, nb);
  k_scan3<<<nb, 256, 0, stream>>>(localsc, bsum, offsets, cursor, Nn, E);
  k_bucket<<<(E + 255) / 256, 256, 0, stream>>>(esrc, edst, erel, eval_, cursor, bucket, E);

  // basis-space aggregation (gathers 256 B rows of the L3-resident Xb)
  k_gather_agg<<<(Nn + 3) / 4, 256, 0, stream>>>(bucket, offsets, w_rel,
                                                 (const unsigned*)Xb, (uint4*)agg, Nn);

  // dense transform: out = agg @ W2
  k_gemm<<<(Nn + 127) / 128, 256, 0, stream>>>(agg, W2T, (float*)d_out, Nn);
}

// Round 4
// 290.571 us; speedup vs baseline: 1.2117x; 1.1244x over previous
//
#include <hip/hip_runtime.h>
#include <stdint.h>

#define D_IN 128
#define D_OUT 128
#define NREL 8
#define NBASE 4

typedef __attribute__((ext_vector_type(8))) short short8;
typedef __attribute__((ext_vector_type(4))) float floatx4;

__device__ __forceinline__ unsigned short f2bf(float f) {
  unsigned int u = __float_as_uint(f);
  u += 0x7fffu + ((u >> 16) & 1u);
  return (unsigned short)(u >> 16);
}
__device__ __forceinline__ unsigned pack2bf(float lo, float hi) {
  return (unsigned)f2bf(lo) | ((unsigned)f2bf(hi) << 16);
}
__device__ __forceinline__ float bflo(unsigned int u) { return __uint_as_float(u << 16); }
__device__ __forceinline__ float bfhi(unsigned int u) { return __uint_as_float(u & 0xffff0000u); }

// ---------- 1) prep: zero counts + cast X fp32->bf16 + build W2T ----------
// W2T[o][c] = w_bases[b][k][o], c = k*4+b  (bf16, [128][512])
__global__ void k_prep(const float4* __restrict__ X, ushort4* __restrict__ Xb, int n4,
                       const float* __restrict__ w_bases, unsigned short* __restrict__ W2T,
                       uint4* __restrict__ counts4, int nc4) {
  int i = blockIdx.x * blockDim.x + threadIdx.x;
  if (i < n4) {
    float4 v = X[i];
    ushort4 o;
    o.x = f2bf(v.x); o.y = f2bf(v.y); o.z = f2bf(v.z); o.w = f2bf(v.w);
    Xb[i] = o;
  }
  if (i < 128 * 512) {
    int o = i >> 9, c = i & 511;
    int k = c >> 2, b = c & 3;
    W2T[i] = f2bf(w_bases[(b * D_IN + k) * D_OUT + o]);
  }
  if (i < nc4) counts4[i] = make_uint4(0u, 0u, 0u, 0u);
}

// ---------- 2) CSR build ----------
__global__ void k_count(const int* __restrict__ dst, int* __restrict__ counts, int E) {
  int i = blockIdx.x * blockDim.x + threadIdx.x;
  if (i < E) atomicAdd(&counts[dst[i]], 1);
}

__global__ void k_scan1(const int* __restrict__ counts, int* __restrict__ localsc,
                        int* __restrict__ bsum, int Nn) {
  __shared__ int s[256];
  int i = blockIdx.x * 256 + threadIdx.x;
  int v = (i < Nn) ? counts[i] : 0;
  s[threadIdx.x] = v;
  __syncthreads();
  for (int off = 1; off < 256; off <<= 1) {
    int t = 0;
    if (threadIdx.x >= off) t = s[threadIdx.x - off];
    __syncthreads();
    s[threadIdx.x] += t;
    __syncthreads();
  }
  if (i < Nn) localsc[i] = s[threadIdx.x] - v;
  if (threadIdx.x == 255) bsum[blockIdx.x] = s[255];
}

// fused scan2+scan3: each block redundantly reduces bsum[0..blockIdx.x) (tiny)
__global__ void k_scan23(const int* __restrict__ localsc, const int* __restrict__ bsum,
                         int* __restrict__ offsets, int* __restrict__ cursor, int Nn, int E) {
  __shared__ int red[256];
  int acc = 0;
  for (int j = threadIdx.x; j < blockIdx.x; j += 256) acc += bsum[j];
  red[threadIdx.x] = acc;
  __syncthreads();
  for (int off = 128; off > 0; off >>= 1) {
    if (threadIdx.x < off) red[threadIdx.x] += red[threadIdx.x + off];
    __syncthreads();
  }
  int pref = red[0];
  int i = blockIdx.x * 256 + threadIdx.x;
  if (i < Nn) {
    int v = localsc[i] + pref;
    offsets[i] = v;
    cursor[i] = v;
  }
  if (i == 0) offsets[Nn] = E;
}

__global__ void k_bucket(const int* __restrict__ src, const int* __restrict__ dst,
                         const int* __restrict__ rel, const float* __restrict__ val,
                         int* __restrict__ cursor, uint2* __restrict__ bucket, int E) {
  int i = blockIdx.x * blockDim.x + threadIdx.x;
  if (i >= E) return;
  int d = dst[i];
  int pos = atomicAdd(&cursor[d], 1);
  bucket[pos] = make_uint2((unsigned)src[i] | ((unsigned)rel[i] << 21), __float_as_uint(val[i]));
}

// ---------- 3) fused: per-dst basis aggregation (LDS) + MFMA transform ----------
struct Acc8 {
  float a00, a10, a20, a30, a01, a11, a21, a31;
  __device__ __forceinline__ void init() {
    a00 = a10 = a20 = a30 = a01 = a11 = a21 = a31 = 0.f;
  }
  __device__ __forceinline__ void add(uint2 m, unsigned xw, const float* wr) {
    float val = __uint_as_float(m.y);
    const float* w = &wr[(m.x >> 21) * 4];
    float c0 = val * w[0], c1 = val * w[1], c2 = val * w[2], c3 = val * w[3];
    float xl = bflo(xw), xh = bfhi(xw);
    a00 += c0 * xl; a10 += c1 * xl; a20 += c2 * xl; a30 += c3 * xl;
    a01 += c0 * xh; a11 += c1 * xh; a21 += c2 * xh; a31 += c3 * xh;
  }
};

// Block = 4 waves, 32 dst rows. Phase 1: wave w aggregates dsts w*8..w*8+7 into
// LDS agg rows (bf16, c=k*4+b layout), 4x-unrolled edge loop for MLP.
// Phase 2: 32x512 @ 512x128 bf16 MFMA; wave w covers output cols w*32..+31.
__global__ __launch_bounds__(256)
void k_agg_gemm(const uint2* __restrict__ bucket, const int* __restrict__ offsets,
                const float* __restrict__ w_rel_g, const unsigned* __restrict__ Xb2,
                const unsigned short* __restrict__ W2T, float* __restrict__ out, int Nn) {
  __shared__ unsigned short aggS[32][520];  // pitch 520: 2-way bank alias (free)
  __shared__ float wr[NREL * NBASE];
  if (threadIdx.x < NREL * NBASE) wr[threadIdx.x] = w_rel_g[threadIdx.x];
  __syncthreads();

  const int wave = threadIdx.x >> 6, lane = threadIdx.x & 63;

  // ---- phase 1: aggregate 8 dsts per wave ----
  for (int j = 0; j < 8; ++j) {
    const int lrow = wave * 8 + j;
    const int dst = blockIdx.x * 32 + lrow;
    Acc8 A;
    A.init();
    if (dst < Nn) {
      const int s = offsets[dst], e = offsets[dst + 1];
      int i = s;
      for (; i + 4 <= e; i += 4) {
        uint2 m0 = bucket[i], m1 = bucket[i + 1], m2 = bucket[i + 2], m3 = bucket[i + 3];
        unsigned y0 = Xb2[((size_t)(m0.x & 0x1FFFFFu) << 6) + lane];
        unsigned y1 = Xb2[((size_t)(m1.x & 0x1FFFFFu) << 6) + lane];
        unsigned y2 = Xb2[((size_t)(m2.x & 0x1FFFFFu) << 6) + lane];
        unsigned y3 = Xb2[((size_t)(m3.x & 0x1FFFFFu) << 6) + lane];
        A.add(m0, y0, wr); A.add(m1, y1, wr); A.add(m2, y2, wr); A.add(m3, y3, wr);
      }
      for (; i < e; ++i) {
        uint2 m = bucket[i];
        unsigned y = Xb2[((size_t)(m.x & 0x1FFFFFu) << 6) + lane];
        A.add(m, y, wr);
      }
    }
    uint4 o;
    o.x = pack2bf(A.a00, A.a10);
    o.y = pack2bf(A.a20, A.a30);
    o.z = pack2bf(A.a01, A.a11);
    o.w = pack2bf(A.a21, A.a31);
    *(uint4*)&aggS[lrow][lane * 8] = o;  // contiguous 1 KB wave write
  }
  __syncthreads();

  // ---- phase 2: 32x128 output tile via 16x16x32 MFMA, K=512 ----
  const int q = lane >> 4, r16 = lane & 15;
  const int wn = wave * 32;
  const floatx4 zero = {0.f, 0.f, 0.f, 0.f};
  floatx4 acc[2][2];
  acc[0][0] = zero; acc[0][1] = zero; acc[1][0] = zero; acc[1][1] = zero;

#pragma unroll 4
  for (int k0 = 0; k0 < 512; k0 += 32) {
    int ka = k0 + q * 8;
    short8 af[2], bfv[2];
    af[0] = *(const short8*)&aggS[r16][ka];
    af[1] = *(const short8*)&aggS[16 + r16][ka];
    bfv[0] = *(const short8*)(W2T + (size_t)(wn + r16) * 512 + ka);
    bfv[1] = *(const short8*)(W2T + (size_t)(wn + 16 + r16) * 512 + ka);
#pragma unroll
    for (int i = 0; i < 2; ++i)
#pragma unroll
      for (int j = 0; j < 2; ++j)
        acc[i][j] = __builtin_amdgcn_mfma_f32_16x16x32_bf16(af[i], bfv[j], acc[i][j], 0, 0, 0);
  }

  // epilogue: C/D layout col=lane&15, row=(lane>>4)*4+p  [m89/m91-verified]
#pragma unroll
  for (int i = 0; i < 2; ++i) {
#pragma unroll
    for (int j = 0; j < 2; ++j) {
#pragma unroll
      for (int p = 0; p < 4; ++p) {
        int row = i * 16 + q * 4 + p;
        int col = wn + j * 16 + r16;
        int grow = blockIdx.x * 32 + row;
        if (grow < Nn) out[(size_t)grow * 128 + col] = acc[i][j][p];
      }
    }
  }
}

extern "C" void kernel_launch(void* const* d_in, const int* in_sizes, int n_in,
                              void* d_out, int out_size, void* d_ws, size_t ws_size,
                              hipStream_t stream) {
  const float* X = (const float*)d_in[0];
  const int* esrc = (const int*)d_in[1];
  const int* edst = (const int*)d_in[2];
  const int* erel = (const int*)d_in[3];
  const float* eval_ = (const float*)d_in[4];
  const float* w_bases = (const float*)d_in[5];
  const float* w_rel = (const float*)d_in[6];
  const int Nn = in_sizes[0] / D_IN;  // 100000
  const int E = in_sizes[1];          // 640000

  char* ws = (char*)d_ws;
  size_t off = 0;
  auto alloc = [&](size_t bytes) -> char* {
    char* p = ws + off;
    off += (bytes + 255) & ~(size_t)255;
    return p;
  };
  unsigned short* Xb = (unsigned short*)alloc((size_t)Nn * D_IN * 2);     // 25.6 MB
  unsigned short* W2T = (unsigned short*)alloc((size_t)128 * 512 * 2);    // 128 KB
  int* counts = (int*)alloc((size_t)Nn * 4);
  int* cursor = (int*)alloc((size_t)Nn * 4);
  int* offsets = (int*)alloc((size_t)(Nn + 1) * 4);
  int* localsc = (int*)alloc((size_t)Nn * 4);
  int* bsum = (int*)alloc(4096);
  uint2* bucket = (uint2*)alloc((size_t)E * 8);                           // 5.1 MB
  (void)ws_size;

  int n4 = Nn * D_IN / 4;  // 3.2M
  int nc4 = Nn / 4;        // counts as uint4
  k_prep<<<(n4 + 255) / 256, 256, 0, stream>>>((const float4*)X, (ushort4*)Xb, n4,
                                               w_bases, W2T, (uint4*)counts, nc4);

  k_count<<<(E + 255) / 256, 256, 0, stream>>>(edst, counts, E);
  int nb = (Nn + 255) / 256;
  k_scan1<<<nb, 256, 0, stream>>>(counts, localsc, bsum, Nn);
  k_scan23<<<nb, 256, 0, stream>>>(localsc, bsum, offsets, cursor, Nn, E);
  k_bucket<<<(E + 255) / 256, 256, 0, stream>>>(esrc, edst, erel, eval_, cursor, bucket, E);

  // fused aggregation + transform
  k_agg_gemm<<<(Nn + 31) / 32, 256, 0, stream>>>(bucket, offsets, w_rel,
                                                 (const unsigned*)Xb, W2T,
                                                 (float*)d_out, Nn);
}